// Round 1
// baseline (3048.204 us; speedup 1.0000x reference)
//
#include <hip/hip_runtime.h>
#include <math.h>

#define H 10
#define BATCH 16384
#define NPAIRS 1024   // T/2
#define SPW 16        // sequences per wave: streams of 6 + 6 + 4

#define LOG2E 1.44269504088896340736f

#if __has_builtin(__builtin_amdgcn_exp2f)
#define EXP2(x) __builtin_amdgcn_exp2f(x)
#else
#define EXP2(x) exp2f(x)
#endif

__device__ __forceinline__ float fast_rcp(float x) { return __builtin_amdgcn_rcpf(x); }

__global__ void __launch_bounds__(64, 2)
lstm_kernel(const float* __restrict__ x,
            const float* __restrict__ WihA, const float* __restrict__ WhhA,
            const float* __restrict__ bihA, const float* __restrict__ bhhA,
            const float* __restrict__ WihB, const float* __restrict__ WhhB,
            const float* __restrict__ bihB, const float* __restrict__ bhhB,
            const float* __restrict__ Wlin, const float* __restrict__ blin,
            float* __restrict__ out)
{
    const int lane    = threadIdx.x;          // block = 1 wave
    const int e_local = lane / H;             // 0..6 (6 => spare lanes)
    const int j       = lane - e_local * H;   // hidden unit owned by this lane
    const bool active = lane < 6 * H;         // 60 active lanes
    const int jj      = active ? j : 0;
    const int g       = active ? e_local : 0;

    // Three independent recurrence streams per lane (in-wave ILP):
    //   stream 0: groups 0..5  -> elems base + 0..5
    //   stream 1: groups 0..5  -> elems base + 6..11
    //   stream 2: groups 0..3  -> elems base + 12..15  (groups 4,5 idle)
    // 16 seqs/wave * 1024 waves = 16384 = BATCH exactly; 1 wave per SIMD,
    // perfectly balanced grid, no tail round.
    const int base  = blockIdx.x * SPW;
    const int elem0 = base + g;
    const int elem1 = base + 6 + g;
    const bool s2   = active && (g < 4);
    const int elem2 = s2 ? (base + 12 + g) : 0;

    // Per-lane weights in registers: lane j owns gate rows {j, H+j, 2H+j, 3H+j}.
    // Shared by all three streams -> no register growth from ILP on weights.
    // Pre-scaled: sigmoid gates (i,f,o) by -log2e, tanh gate (g) by +2log2e,
    // so all activations use raw exp2. (Bitwise-identical math to prior kernel.)
    float wA[4][H], wB[4][H];
    float bA[4], bB[4], wxA0[4], wxA1[4], wxB[4];
#pragma unroll
    for (int q = 0; q < 4; ++q) {
        const float s = (q == 2) ? (2.0f * LOG2E) : (-LOG2E);
        const int row = q * H + jj;
        bA[q]   = s * (bihA[row] + bhhA[row]);
        bB[q]   = s * (bihB[row] + bhhB[row]);
        wxA0[q] = s * WihA[row * 2 + 0];
        wxA1[q] = s * WihA[row * 2 + 1];
        wxB[q]  = s * WihB[row];
#pragma unroll
        for (int k = 0; k < H; ++k) {
            wA[q][k] = s * WhhA[row * H + k];
            wB[q][k] = s * WhhB[row * H + k];
        }
    }
    // Pin weights as opaque register values (defeats in-loop rematerialization
    // / AGPR parking with accvgpr round-trips).
#pragma unroll
    for (int q = 0; q < 4; ++q) {
        asm volatile("" : "+v"(bA[q]), "+v"(bB[q]), "+v"(wxA0[q]),
                          "+v"(wxA1[q]), "+v"(wxB[q]));
#pragma unroll
        for (int k = 0; k < H; ++k) {
            asm volatile("" : "+v"(wA[q][k]), "+v"(wB[q][k]));
        }
    }

    const int base4 = (e_local * H) << 2;     // bpermute byte addr of group base

    const float4* __restrict__ xr0 = (const float4*)x + (size_t)elem0 * NPAIRS;
    const float4* __restrict__ xr1 = (const float4*)x + (size_t)elem1 * NPAIRS;
    const float4* __restrict__ xr2 = (const float4*)x + (size_t)elem2 * NPAIRS;

    // ---- LSTM cell bodies (identical numerics to the verified kernel) ----
    auto cellB = [&](float& h, float& c, float xx) {
        float y0 = fmaf(wxB[0], xx, bB[0]);   // i (scaled -log2e)
        float y1 = fmaf(wxB[1], xx, bB[1]);   // f (scaled -log2e)
        float y2 = fmaf(wxB[2], xx, bB[2]);   // g (scaled +2log2e)
        float y3 = fmaf(wxB[3], xx, bB[3]);   // o (scaled -log2e)
#pragma unroll
        for (int k = 0; k < H; ++k) {
            const float hk = __int_as_float(
                __builtin_amdgcn_ds_bpermute(base4 + (k << 2), __float_as_int(h)));
            y0 = fmaf(wB[0][k], hk, y0);
            y1 = fmaf(wB[1][k], hk, y1);
            y2 = fmaf(wB[2][k], hk, y2);
            y3 = fmaf(wB[3][k], hk, y3);
        }
        const float ef = EXP2(y1);
        const float ei = EXP2(y0);
        const float eg = EXP2(-__builtin_fabsf(y2));
        const float sf = fast_rcp(1.0f + ef);
        const float d1 = (1.0f + ei) * (1.0f + eg);
        const float it = __builtin_copysignf((1.0f - eg) * fast_rcp(d1), y2);
        const float cn = fmaf(sf, c, it);
        const float eo = EXP2(y3);
        const float ec = EXP2((-2.0f * LOG2E) * __builtin_fabsf(cn));
        const float d2 = (1.0f + eo) * (1.0f + ec);
        h = __builtin_copysignf((1.0f - ec) * fast_rcp(d2), cn);
        c = cn;
    };

    auto cellA = [&](float& h, float& c, float x0, float x1) {
        float y0 = fmaf(wxA1[0], x1, fmaf(wxA0[0], x0, bA[0]));
        float y1 = fmaf(wxA1[1], x1, fmaf(wxA0[1], x0, bA[1]));
        float y2 = fmaf(wxA1[2], x1, fmaf(wxA0[2], x0, bA[2]));
        float y3 = fmaf(wxA1[3], x1, fmaf(wxA0[3], x0, bA[3]));
#pragma unroll
        for (int k = 0; k < H; ++k) {
            const float hk = __int_as_float(
                __builtin_amdgcn_ds_bpermute(base4 + (k << 2), __float_as_int(h)));
            y0 = fmaf(wA[0][k], hk, y0);
            y1 = fmaf(wA[1][k], hk, y1);
            y2 = fmaf(wA[2][k], hk, y2);
            y3 = fmaf(wA[3][k], hk, y3);
        }
        const float ef = EXP2(y1);
        const float ei = EXP2(y0);
        const float eg = EXP2(-__builtin_fabsf(y2));
        const float sf = fast_rcp(1.0f + ef);
        const float d1 = (1.0f + ei) * (1.0f + eg);
        const float it = __builtin_copysignf((1.0f - eg) * fast_rcp(d1), y2);
        const float cn = fmaf(sf, c, it);
        const float eo = EXP2(y3);
        const float ec = EXP2((-2.0f * LOG2E) * __builtin_fabsf(cn));
        const float d2 = (1.0f + eo) * (1.0f + ec);
        h = __builtin_copysignf((1.0f - ec) * fast_rcp(d2), cn);
        c = cn;
    };

    float h0 = 0.0f, c0 = 0.0f;
    float h1 = 0.0f, c1 = 0.0f;
    float h2 = 0.0f, c2 = 0.0f;
    float4 xp0 = xr0[0], xp1 = xr1[0], xp2 = xr2[0];

#pragma unroll 1
    for (int p = 0; p < NPAIRS; ++p) {
        const int pn = (p + 1 < NPAIRS) ? (p + 1) : p;
        const float4 xn0 = xr0[pn];           // prefetch off the h->h chain
        const float4 xn1 = xr1[pn];
        const float4 xn2 = xr2[pn];

        // cell B: input = x[:, 2p, :1] — three independent streams; the
        // scheduler hides each stream's bpermute/exp2 latency under the
        // other streams' FMA work.
        cellB(h0, c0, xp0.x);
        cellB(h1, c1, xp1.x);
        cellB(h2, c2, xp2.x);

        // cell A: input = x[:, 2p+1, :]
        cellA(h0, c0, xp0.z, xp0.w);
        cellA(h1, c1, xp1.z, xp1.w);
        cellA(h2, c2, xp2.z, xp2.w);

        xp0 = xn0; xp1 = xn1; xp2 = xn2;
    }

    // ---- output: sigmoid(h . Wlin + blin), reduce across the 10-lane group ----
    auto reduce10 = [&](float hv) -> float {
        const float v = Wlin[jj] * hv;
        float s = v;
#pragma unroll
        for (int k = 1; k < H; ++k) {
            s += __int_as_float(
                __builtin_amdgcn_ds_bpermute(base4 + (k << 2), __float_as_int(v)));
        }
        return s;
    };

    const float s0 = reduce10(h0);
    const float s1 = reduce10(h1);
    const float s2v = reduce10(h2);

    if (active && j == 0) {
        const float bl = blin[0];
        out[elem0] = fast_rcp(1.0f + EXP2(-LOG2E * (s0 + bl)));
        out[elem1] = fast_rcp(1.0f + EXP2(-LOG2E * (s1 + bl)));
        if (g < 4)
            out[elem2] = fast_rcp(1.0f + EXP2(-LOG2E * (s2v + bl)));
    }
}

extern "C" void kernel_launch(void* const* d_in, const int* in_sizes, int n_in,
                              void* d_out, int out_size, void* d_ws, size_t ws_size,
                              hipStream_t stream) {
    const float* x    = (const float*)d_in[0];
    const float* WihA = (const float*)d_in[1];
    const float* WhhA = (const float*)d_in[2];
    const float* bihA = (const float*)d_in[3];
    const float* bhhA = (const float*)d_in[4];
    const float* WihB = (const float*)d_in[5];
    const float* WhhB = (const float*)d_in[6];
    const float* bihB = (const float*)d_in[7];
    const float* bhhB = (const float*)d_in[8];
    const float* Wlin = (const float*)d_in[9];
    const float* blin = (const float*)d_in[10];
    float* out = (float*)d_out;

    const int grid = BATCH / SPW;             // 1024 one-wave blocks = 1/SIMD
    hipLaunchKernelGGL(lstm_kernel, dim3(grid), dim3(64), 0, stream,
                       x, WihA, WhhA, bihA, bhhA, WihB, WhhB, bihB, bhhB,
                       Wlin, blin, out);
}

// Round 2
// 1163.086 us; speedup vs baseline: 2.6208x; 2.6208x over previous
//
#include <hip/hip_runtime.h>
#include <math.h>

#define H 10
#define BATCH 16384
#define NPAIRS 1024   // T/2
#define EPW 6         // sequences per 64-lane wave, 60 active lanes
#define GSTRIDE 12    // LDS floats per group (pad 10 -> 12: conflict-free b128 reads)

#define LOG2E 1.44269504088896340736f

#if __has_builtin(__builtin_amdgcn_exp2f)
#define EXP2(x) __builtin_amdgcn_exp2f(x)
#else
#define EXP2(x) exp2f(x)
#endif

__device__ __forceinline__ float fast_rcp(float x) { return __builtin_amdgcn_rcpf(x); }

__global__ void __launch_bounds__(64, 2)
lstm_kernel(const float* __restrict__ x,
            const float* __restrict__ WihA, const float* __restrict__ WhhA,
            const float* __restrict__ bihA, const float* __restrict__ bhhA,
            const float* __restrict__ WihB, const float* __restrict__ WhhB,
            const float* __restrict__ bihB, const float* __restrict__ bhhB,
            const float* __restrict__ Wlin, const float* __restrict__ blin,
            float* __restrict__ out)
{
    const int lane    = threadIdx.x;          // block = 1 wave
    const int e_local = lane / H;             // 0..6 (6 => spare lanes)
    const int j       = lane - e_local * H;   // hidden unit owned by this lane
    const bool active = lane < EPW * H;
    const int elem    = blockIdx.x * EPW + e_local;
    const bool valid  = active && (elem < BATCH);
    const int jj      = active ? j : 0;
    const int elem_c  = valid ? elem : 0;

    // h-broadcast buffer: group g's h vector lives at hbuf[g*12 .. g*12+9].
    // Stride 12 floats (48 B): 16B-aligned bases, and the 6 groups' b128/b64
    // reads hit disjoint bank sets -> zero read conflicts. Spare lanes
    // (60..63, e_local=6) write to 72..75 and read 72..81 (garbage, discarded).
    __shared__ __align__(16) float hbuf[84];
    const int waddr = active ? (e_local * GSTRIDE + j) : (72 + (lane - 60));
    const int rbase = e_local * GSTRIDE;      // inactive: 72, reads stay < 84

    // Per-lane weights in registers: lane j owns gate rows {j, H+j, 2H+j, 3H+j}.
    // Pre-scaled: sigmoid gates (i,f,o) by -log2e, tanh gate (g) by +2log2e,
    // so all activations use raw exp2. (Numerics identical to verified kernel.)
    float wA[4][H], wB[4][H];
    float bA[4], bB[4], wxA0[4], wxA1[4], wxB[4];
#pragma unroll
    for (int g = 0; g < 4; ++g) {
        const float s = (g == 2) ? (2.0f * LOG2E) : (-LOG2E);
        const int row = g * H + jj;
        bA[g]   = s * (bihA[row] + bhhA[row]);
        bB[g]   = s * (bihB[row] + bhhB[row]);
        wxA0[g] = s * WihA[row * 2 + 0];
        wxA1[g] = s * WihA[row * 2 + 1];
        wxB[g]  = s * WihB[row];
#pragma unroll
        for (int k = 0; k < H; ++k) {
            wA[g][k] = s * WhhA[row * H + k];
            wB[g][k] = s * WhhB[row * H + k];
        }
    }
    // Pin weights as opaque register values (defeats in-loop rematerialization
    // / AGPR parking).
#pragma unroll
    for (int g = 0; g < 4; ++g) {
        asm volatile("" : "+v"(bA[g]), "+v"(bB[g]), "+v"(wxA0[g]),
                          "+v"(wxA1[g]), "+v"(wxB[g]));
#pragma unroll
        for (int k = 0; k < H; ++k) {
            asm volatile("" : "+v"(wA[g][k]), "+v"(wB[g][k]));
        }
    }

    const float4* __restrict__ xr = (const float4*)x + (size_t)elem_c * NPAIRS;

    float h = 0.0f, c = 0.0f;
    float4 xp = xr[0];                        // prefetched current pair

#pragma unroll 2
    for (int p = 0; p < NPAIRS; ++p) {
        const int pn = (p + 1 < NPAIRS) ? (p + 1) : p;
        const float4 xnext = xr[pn];          // off the critical h->h chain

        // ================= cell B: input = x[:, 2p, :1] =================
        {
            // h-broadcast: 1 ds_write + 2 ds_read_b128 + 1 ds_read_b64
            // (was 10 ds_bpermute). Same-wave DS ops complete in order ->
            // no barrier needed for the RAW through hbuf.
            hbuf[waddr] = h;
            float y0 = fmaf(wxB[0], xp.x, bB[0]);   // i (scaled -log2e)
            float y1 = fmaf(wxB[1], xp.x, bB[1]);   // f (scaled -log2e)
            float y2 = fmaf(wxB[2], xp.x, bB[2]);   // g (scaled +2log2e)
            float y3 = fmaf(wxB[3], xp.x, bB[3]);   // o (scaled -log2e)
            const float4 ha = *reinterpret_cast<const float4*>(&hbuf[rbase]);
            const float4 hb = *reinterpret_cast<const float4*>(&hbuf[rbase + 4]);
            const float2 hc = *reinterpret_cast<const float2*>(&hbuf[rbase + 8]);
            float hh[H] = {ha.x, ha.y, ha.z, ha.w, hb.x, hb.y, hb.z, hb.w,
                           hc.x, hc.y};
#pragma unroll
            for (int k = 0; k < H; ++k) {
                y0 = fmaf(wB[0][k], hh[k], y0);
                y1 = fmaf(wB[1][k], hh[k], y1);
                y2 = fmaf(wB[2][k], hh[k], y2);
                y3 = fmaf(wB[3][k], hh[k], y3);
            }
            // fused: sigm(f)*c + sigm(i)*tanh(g)   [single rcp for i*g term]
            const float ef = EXP2(y1);
            const float ei = EXP2(y0);
            const float eg = EXP2(-__builtin_fabsf(y2));
            const float sf = fast_rcp(1.0f + ef);
            const float d1 = (1.0f + ei) * (1.0f + eg);
            const float it = __builtin_copysignf((1.0f - eg) * fast_rcp(d1), y2);
            const float cn = fmaf(sf, c, it);
            // fused: sigm(o)*tanh(c)               [single rcp]
            const float eo = EXP2(y3);
            const float ec = EXP2((-2.0f * LOG2E) * __builtin_fabsf(cn));
            const float d2 = (1.0f + eo) * (1.0f + ec);
            h = __builtin_copysignf((1.0f - ec) * fast_rcp(d2), cn);
            c = cn;
        }

        // ================= cell A: input = x[:, 2p+1, :] =================
        {
            hbuf[waddr] = h;
            float y0 = fmaf(wxA1[0], xp.w, fmaf(wxA0[0], xp.z, bA[0]));
            float y1 = fmaf(wxA1[1], xp.w, fmaf(wxA0[1], xp.z, bA[1]));
            float y2 = fmaf(wxA1[2], xp.w, fmaf(wxA0[2], xp.z, bA[2]));
            float y3 = fmaf(wxA1[3], xp.w, fmaf(wxA0[3], xp.z, bA[3]));
            const float4 ha = *reinterpret_cast<const float4*>(&hbuf[rbase]);
            const float4 hb = *reinterpret_cast<const float4*>(&hbuf[rbase + 4]);
            const float2 hc = *reinterpret_cast<const float2*>(&hbuf[rbase + 8]);
            float hh[H] = {ha.x, ha.y, ha.z, ha.w, hb.x, hb.y, hb.z, hb.w,
                           hc.x, hc.y};
#pragma unroll
            for (int k = 0; k < H; ++k) {
                y0 = fmaf(wA[0][k], hh[k], y0);
                y1 = fmaf(wA[1][k], hh[k], y1);
                y2 = fmaf(wA[2][k], hh[k], y2);
                y3 = fmaf(wA[3][k], hh[k], y3);
            }
            const float ef = EXP2(y1);
            const float ei = EXP2(y0);
            const float eg = EXP2(-__builtin_fabsf(y2));
            const float sf = fast_rcp(1.0f + ef);
            const float d1 = (1.0f + ei) * (1.0f + eg);
            const float it = __builtin_copysignf((1.0f - eg) * fast_rcp(d1), y2);
            const float cn = fmaf(sf, c, it);
            const float eo = EXP2(y3);
            const float ec = EXP2((-2.0f * LOG2E) * __builtin_fabsf(cn));
            const float d2 = (1.0f + eo) * (1.0f + ec);
            h = __builtin_copysignf((1.0f - ec) * fast_rcp(d2), cn);
            c = cn;
        }

        xp = xnext;
    }

    // ---- output: sigmoid(h . Wlin + blin), reduce across the 10-lane group ----
    // Same write+vector-read mechanism; accumulation order k=0..9 matches the
    // verified kernel's order for lane j==0 (v0 + v1 + ... + v9).
    {
        const float v = Wlin[jj] * h;
        hbuf[waddr] = v;
        const float4 ha = *reinterpret_cast<const float4*>(&hbuf[rbase]);
        const float4 hb = *reinterpret_cast<const float4*>(&hbuf[rbase + 4]);
        const float2 hc = *reinterpret_cast<const float2*>(&hbuf[rbase + 8]);
        const float s = ((ha.x + ha.y) + (ha.z + ha.w)) +
                        ((hb.x + hb.y) + (hb.z + hb.w)) + (hc.x + hc.y);
        if (valid && j == 0) {
            const float y = s + blin[0];
            out[elem] = fast_rcp(1.0f + EXP2(-LOG2E * y));
        }
    }
}

extern "C" void kernel_launch(void* const* d_in, const int* in_sizes, int n_in,
                              void* d_out, int out_size, void* d_ws, size_t ws_size,
                              hipStream_t stream) {
    const float* x    = (const float*)d_in[0];
    const float* WihA = (const float*)d_in[1];
    const float* WhhA = (const float*)d_in[2];
    const float* bihA = (const float*)d_in[3];
    const float* bhhA = (const float*)d_in[4];
    const float* WihB = (const float*)d_in[5];
    const float* WhhB = (const float*)d_in[6];
    const float* bihB = (const float*)d_in[7];
    const float* bhhB = (const float*)d_in[8];
    const float* Wlin = (const float*)d_in[9];
    const float* blin = (const float*)d_in[10];
    float* out = (float*)d_out;

    const int grid = (BATCH + EPW - 1) / EPW;  // 2731 one-wave blocks
    hipLaunchKernelGGL(lstm_kernel, dim3(grid), dim3(64), 0, stream,
                       x, WihA, WhhA, bihA, bhhA, WihB, WhhB, bihB, bhhB,
                       Wlin, blin, out);
}